// Round 3
// 401.458 us; speedup vs baseline: 1.0775x; 1.0775x over previous
//
#include <hip/hip_runtime.h>

#define H     1024
#define IMG   2048
#define MID   512
#define VOCAB 32000
#define NR    576
#define IN1   4096
#define IN2   3072
#define VN    (NR * IMG)        // 1179648
#define WN    (MID * IMG)       // 1048576

typedef unsigned short u16;
typedef unsigned int u32;
typedef __attribute__((ext_vector_type(8))) short short8;
typedef __attribute__((ext_vector_type(4))) float f32x4;

__device__ __forceinline__ float wave_sum(float v) {
  #pragma unroll
  for (int off = 32; off > 0; off >>= 1) v += __shfl_down(v, off, 64);
  return v;
}
__device__ __forceinline__ float sigf(float x) { return 1.0f / (1.0f + __expf(-x)); }
__device__ __forceinline__ float dot4(float4 a, float4 b) {
  return a.x * b.x + a.y * b.y + a.z * b.z + a.w * b.w;
}
__device__ __forceinline__ u32 f2bfbits(float f) {  // RNE
  union { float f; u32 i; } c; c.f = f;
  return (c.i + 0x7fffu + ((c.i >> 16) & 1u)) >> 16;
}

// ---- prep: blocks [0,1088) cvt V+lvw->bf16; [1088,1096) x1 h2/emb; [1096,1160) vbar ----
__global__ __launch_bounds__(256) void k_prep(const float* __restrict__ V,
                                              const float* __restrict__ lvw,
                                              const float* __restrict__ h2,
                                              const float* __restrict__ emb,
                                              const int* __restrict__ w,
                                              u16* __restrict__ Vbf, u16* __restrict__ Wbf,
                                              float* __restrict__ x1) {
  int b = blockIdx.x;
  int t = threadIdx.x;
  if (b < 1088) {
    long i8 = (long)(b * 256 + t) * 8;   // covers 2228224 = VN + WN
    const float* src; u16* dst; long off;
    if (i8 < VN) { src = V; dst = Vbf; off = i8; }
    else         { src = lvw; dst = Wbf; off = i8 - VN; }
    float4 qa = *(const float4*)(src + off);
    float4 qb = *(const float4*)(src + off + 4);
    u32 p0 = f2bfbits(qa.x) | (f2bfbits(qa.y) << 16);
    u32 p1 = f2bfbits(qa.z) | (f2bfbits(qa.w) << 16);
    u32 p2 = f2bfbits(qb.x) | (f2bfbits(qb.y) << 16);
    u32 p3 = f2bfbits(qb.z) | (f2bfbits(qb.w) << 16);
    *(uint4*)(dst + off) = make_uint4(p0, p1, p2, p3);
  } else if (b < 1096) {
    int tt = (b - 1088) * 256 + t;       // 0..2047
    if (tt < H) x1[tt] = h2[tt];
    else {
      int j = tt - H;
      x1[3072 + j] = emb[(long)w[0] * 1024 + j];
    }
  } else {
    // vbar: block bb covers 32 cols; thread: col = bb*32 + (t&31), row-chunk t>>5 (8 x 72)
    __shared__ float red[8][32];
    int bb = b - 1096;                   // 0..63
    int c = bb * 32 + (t & 31);
    int rc = t >> 5;
    float s = 0.f;
    for (int r = rc * 72; r < rc * 72 + 72; r++) s += V[(long)r * IMG + c];
    red[rc][t & 31] = s;
    __syncthreads();
    if (t < 32) {
      float tot = 0.f;
      #pragma unroll
      for (int j = 0; j < 8; j++) tot += red[j][t];
      x1[H + bb * 32 + t] = tot * (1.0f / 576.0f);
    }
  }
}

// ---- merged: blocks [0,288) vt GEMM tiles; [288,1312) LSTM1 rows ----
// Both sides depend only on k_prep outputs (Vbf/Wbf for GEMM; x1 for LSTM1) + raw inputs.
__global__ __launch_bounds__(256) void k_gemm_lstm1(const u16* __restrict__ Vbf,
                                                    const u16* __restrict__ Wbf,
                                                    float* __restrict__ vtp,
                                                    const float* __restrict__ Wih,
                                                    const float* __restrict__ Whh,
                                                    const float* __restrict__ bih,
                                                    const float* __restrict__ bhh,
                                                    const float* __restrict__ x1,
                                                    const float* __restrict__ h1,
                                                    const float* __restrict__ c1,
                                                    float* __restrict__ h1n,
                                                    float* __restrict__ out_h,
                                                    float* __restrict__ out_c) {
  int t = threadIdx.x;
  int b = blockIdx.x;
  if (b < 288) {
    // vt GEMM via MFMA bf16: 64x64 tile/block, 2x2 waves of 32x32, K-chunk of 512
    int z = b / 72, rem = b % 72;
    int bx = rem % 9, by = rem / 9;
    int wave = t >> 6, lane = t & 63;
    int wm = wave >> 1, wn = wave & 1;
    int m0 = bx * 64 + wm * 32;
    int n0 = by * 64 + wn * 32;
    int ri = lane & 15, quad = lane >> 4;
    const u16* aptr0 = Vbf + (long)(m0 + ri) * IMG + z * 512 + quad * 8;
    const u16* aptr1 = aptr0 + 16 * IMG;
    const u16* bptr0 = Wbf + (long)(n0 + ri) * IMG + z * 512 + quad * 8;
    const u16* bptr1 = bptr0 + 16 * IMG;
    f32x4 acc00 = {0.f,0.f,0.f,0.f}, acc01 = {0.f,0.f,0.f,0.f};
    f32x4 acc10 = {0.f,0.f,0.f,0.f}, acc11 = {0.f,0.f,0.f,0.f};
    #pragma unroll 4
    for (int ks = 0; ks < 16; ks++) {
      int ko = ks * 32;
      short8 a0 = *(const short8*)(aptr0 + ko);
      short8 a1 = *(const short8*)(aptr1 + ko);
      short8 b0 = *(const short8*)(bptr0 + ko);
      short8 b1 = *(const short8*)(bptr1 + ko);
      acc00 = __builtin_amdgcn_mfma_f32_16x16x32_bf16(a0, b0, acc00, 0, 0, 0);
      acc01 = __builtin_amdgcn_mfma_f32_16x16x32_bf16(a0, b1, acc01, 0, 0, 0);
      acc10 = __builtin_amdgcn_mfma_f32_16x16x32_bf16(a1, b0, acc10, 0, 0, 0);
      acc11 = __builtin_amdgcn_mfma_f32_16x16x32_bf16(a1, b1, acc11, 0, 0, 0);
    }
    float* base = vtp + (long)z * (NR * MID);
    #pragma unroll
    for (int r = 0; r < 4; r++) {
      int row = quad * 4 + r;
      base[(long)(m0 + row) * MID + n0 + ri]           = acc00[r];
      base[(long)(m0 + row) * MID + n0 + 16 + ri]      = acc01[r];
      base[(long)(m0 + 16 + row) * MID + n0 + ri]      = acc10[r];
      base[(long)(m0 + 16 + row) * MID + n0 + 16 + ri] = acc11[r];
    }
  } else {
    // LSTM1: block = hidden element k; wave w computes gate row k + w*H
    __shared__ float gate[4];
    int w = t >> 6, l = t & 63;
    int k = b - 288;                      // 0..1023
    int row = k + w * H;
    const float4* W4  = (const float4*)(Wih + (long)row * IN1);
    const float4* Wh4 = (const float4*)(Whh + (long)row * H);
    const float4* X4  = (const float4*)x1;
    const float4* H14 = (const float4*)h1;
    float acc = 0.f;
    #pragma unroll
    for (int c = 0; c < 16; c++) { int idx = c * 64 + l; acc += dot4(W4[idx], X4[idx]); }
    #pragma unroll
    for (int c = 0; c < 4; c++)  { int idx = c * 64 + l; acc += dot4(Wh4[idx], H14[idx]); }
    acc = wave_sum(acc);
    if (l == 0) gate[w] = acc + bih[row] + bhh[row];
    __syncthreads();
    if (t == 0) {
      float i  = sigf(gate[0]);
      float f  = sigf(gate[1]);
      float gg = tanhf(gate[2]);
      float o  = sigf(gate[3]);
      float c  = f * c1[k] + i * gg;
      float h  = o * tanhf(c);
      h1n[k] = h; out_h[k] = h; out_c[k] = c;
    }
  }
}

// ---- h1t = lh_w @ h1n + lh_b ----
__global__ void k_h1t(const float* __restrict__ lhw, const float* __restrict__ lhb,
                      const float* __restrict__ h1n, float* __restrict__ h1t) {
  int w = threadIdx.x >> 6, l = threadIdx.x & 63;
  int row = blockIdx.x * 4 + w;
  const float4* W4 = (const float4*)(lhw + (long)row * H);
  const float4* X4 = (const float4*)h1n;
  float acc = 0.f;
  #pragma unroll
  for (int c = 0; c < 4; c++) { int idx = c * 64 + l; acc += dot4(W4[idx], X4[idx]); }
  acc = wave_sum(acc);
  if (l == 0) h1t[row] = acc + lhb[row];
}

// ---- attention logits: reads 4 vtp partials + bias inline ----
__global__ void k_att(const float* __restrict__ vtp, const float* __restrict__ lvb,
                      const float* __restrict__ h1t,
                      const float* __restrict__ attw, const float* __restrict__ attb,
                      float* __restrict__ logits) {
  int w = threadIdx.x >> 6, l = threadIdx.x & 63;
  int row = blockIdx.x * 4 + w;   // 576 rows
  const float4* A4 = (const float4*)attw;
  const float4* T4 = (const float4*)h1t;
  const float4* B4 = (const float4*)lvb;
  float acc = 0.f;
  #pragma unroll
  for (int ch = 0; ch < 2; ch++) {
    int idx = 2 * l + ch;          // float4 index within MID
    const float4* p = (const float4*)(vtp + (long)row * MID) + idx;
    float4 s = p[0];
    float4 s1 = p[NR * MID / 4];
    float4 s2 = p[2 * NR * MID / 4];
    float4 s3 = p[3 * NR * MID / 4];
    float4 bb = B4[idx], tt = T4[idx], aa = A4[idx];
    float vx = s.x + s1.x + s2.x + s3.x + bb.x + tt.x;
    float vy = s.y + s1.y + s2.y + s3.y + bb.y + tt.y;
    float vz = s.z + s1.z + s2.z + s3.z + bb.z + tt.z;
    float vw = s.w + s1.w + s2.w + s3.w + bb.w + tt.w;
    acc += tanhf(vx) * aa.x + tanhf(vy) * aa.y + tanhf(vz) * aa.z + tanhf(vw) * aa.w;
  }
  acc = wave_sum(acc);
  if (l == 0) logits[row] = acc + attb[0];
}

// ---- fused softmax + weighted sum: 64 blocks x 256 threads; block b -> 32 cols, 8-way row split ----
__global__ __launch_bounds__(256) void k_smwv(const float* __restrict__ logits,
                                              const float* __restrict__ V,
                                              float* __restrict__ v) {
  __shared__ float arr[576];
  __shared__ float r8[8];
  __shared__ float red[8][32];
  int t = threadIdx.x;
  int wv = t >> 6, l = t & 63;
  float x0 = logits[t];
  float x1 = logits[t + 256];
  float x2 = (t < 64) ? logits[t + 512] : -3.0e38f;
  float m = fmaxf(fmaxf(x0, x1), x2);
  #pragma unroll
  for (int off = 32; off > 0; off >>= 1) m = fmaxf(m, __shfl_down(m, off, 64));
  if (l == 0) r8[wv] = m;
  __syncthreads();
  float bm = fmaxf(fmaxf(r8[0], r8[1]), fmaxf(r8[2], r8[3]));
  float e0 = __expf(x0 - bm);
  float e1 = __expf(x1 - bm);
  float e2 = (t < 64) ? __expf(x2 - bm) : 0.f;
  arr[t] = e0; arr[t + 256] = e1;
  if (t < 64) arr[t + 512] = e2;
  float s = wave_sum(e0 + e1 + e2);
  if (l == 0) r8[4 + wv] = s;
  __syncthreads();              // arr + partial sums ready
  float inv = 1.0f / (r8[4] + r8[5] + r8[6] + r8[7]);
  int c = blockIdx.x * 32 + (t & 31);
  int rc = t >> 5;              // 0..7, 72 rows each
  float acc = 0.f;
  #pragma unroll 8
  for (int r = rc * 72; r < rc * 72 + 72; r++) acc += arr[r] * V[(long)r * IMG + c];
  red[rc][t & 31] = acc;
  __syncthreads();
  if (t < 32) {
    float tot = 0.f;
    #pragma unroll
    for (int j = 0; j < 8; j++) tot += red[j][t];
    v[blockIdx.x * 32 + t] = tot * inv;
  }
}

// ---- fused LSTM2 ----
__global__ __launch_bounds__(256) void k_lstm2(const float* __restrict__ Wih,
                                               const float* __restrict__ Whh,
                                               const float* __restrict__ bih,
                                               const float* __restrict__ bhh,
                                               const float* __restrict__ v,
                                               const float* __restrict__ h1n,
                                               const float* __restrict__ h2,
                                               const float* __restrict__ c2,
                                               float* __restrict__ h2n,
                                               float* __restrict__ out_h,
                                               float* __restrict__ out_c) {
  __shared__ float gate[4];
  int w = threadIdx.x >> 6, l = threadIdx.x & 63;
  int k = blockIdx.x;
  int row = k + w * H;
  const float4* W4  = (const float4*)(Wih + (long)row * IN2);
  const float4* Wh4 = (const float4*)(Whh + (long)row * H);
  const float4* Vv4 = (const float4*)v;
  const float4* H1n = (const float4*)h1n;
  const float4* H24 = (const float4*)h2;
  float acc = 0.f;
  #pragma unroll
  for (int c = 0; c < 8; c++) { int idx = c * 64 + l; acc += dot4(W4[idx], Vv4[idx]); }
  #pragma unroll
  for (int c = 0; c < 4; c++) { int idx = c * 64 + l; acc += dot4(W4[512 + idx], H1n[idx]); }
  #pragma unroll
  for (int c = 0; c < 4; c++) { int idx = c * 64 + l; acc += dot4(Wh4[idx], H24[idx]); }
  acc = wave_sum(acc);
  if (l == 0) gate[w] = acc + bih[row] + bhh[row];
  __syncthreads();
  if (threadIdx.x == 0) {
    float i  = sigf(gate[0]);
    float f  = sigf(gate[1]);
    float gg = tanhf(gate[2]);
    float o  = sigf(gate[3]);
    float c  = f * c2[k] + i * gg;
    float h  = o * tanhf(c);
    h2n[k] = h; out_h[k] = h; out_c[k] = c;
  }
}

// ---- output logits ----
__global__ void k_out(const float* __restrict__ linw, const float* __restrict__ linb,
                      const float* __restrict__ h2n, float* __restrict__ o) {
  int w = threadIdx.x >> 6, l = threadIdx.x & 63;
  int row = blockIdx.x * 4 + w;
  const float4* W4 = (const float4*)(linw + (long)row * H);
  const float4* X4 = (const float4*)h2n;
  float acc = 0.f;
  #pragma unroll
  for (int c = 0; c < 4; c++) { int idx = c * 64 + l; acc += dot4(W4[idx], X4[idx]); }
  acc = wave_sum(acc);
  if (l == 0) o[row] = acc + linb[row];
}

extern "C" void kernel_launch(void* const* d_in, const int* in_sizes, int n_in,
                              void* d_out, int out_size, void* d_ws, size_t ws_size,
                              hipStream_t stream) {
  const float* V    = (const float*)d_in[0];
  const int*   w    = (const int*)d_in[1];
  const float* h1   = (const float*)d_in[2];
  const float* c1   = (const float*)d_in[3];
  const float* h2   = (const float*)d_in[4];
  const float* c2   = (const float*)d_in[5];
  const float* emb  = (const float*)d_in[6];
  const float* Wih1 = (const float*)d_in[7];
  const float* Whh1 = (const float*)d_in[8];
  const float* bih1 = (const float*)d_in[9];
  const float* bhh1 = (const float*)d_in[10];
  const float* Wih2 = (const float*)d_in[11];
  const float* Whh2 = (const float*)d_in[12];
  const float* bih2 = (const float*)d_in[13];
  const float* bhh2 = (const float*)d_in[14];
  const float* lvw  = (const float*)d_in[15];
  const float* lvb  = (const float*)d_in[16];
  const float* lhw  = (const float*)d_in[17];
  const float* lhb  = (const float*)d_in[18];
  const float* attw = (const float*)d_in[19];
  const float* attb = (const float*)d_in[20];
  const float* linw = (const float*)d_in[21];
  const float* linb = (const float*)d_in[22];

  float* ws     = (float*)d_ws;
  float* x1     = ws;              // 4096
  float* h1n    = ws + 4096;       // 1024
  float* h1t    = ws + 5120;       // 512
  float* logits = ws + 5632;       // 576 (pad to 640)
  float* v      = ws + 6272;       // 2048
  float* h2n    = ws + 8320;       // 1024
  float* vtp    = ws + 9344;       // 4 * 294912 = 1179648
  u16*   Vbf    = (u16*)(ws + 1188992);   // 1179648 u16
  u16*   Wbf    = Vbf + VN;               // 1048576 u16

  float* out    = (float*)d_out;
  float* out_o  = out;
  float* out_h1 = out + VOCAB;
  float* out_c1 = out + VOCAB + H;
  float* out_h2 = out + VOCAB + 2 * H;
  float* out_c2 = out + VOCAB + 3 * H;

  k_prep<<<1160, 256, 0, stream>>>(V, lvw, h2, emb, w, Vbf, Wbf, x1);
  k_gemm_lstm1<<<1312, 256, 0, stream>>>(Vbf, Wbf, vtp, Wih1, Whh1, bih1, bhh1,
                                         x1, h1, c1, h1n, out_h1, out_c1);
  k_h1t<<<128, 256, 0, stream>>>(lhw, lhb, h1n, h1t);
  k_att<<<144, 256, 0, stream>>>(vtp, lvb, h1t, attw, attb, logits);
  k_smwv<<<64, 256, 0, stream>>>(logits, V, v);
  k_lstm2<<<1024, 256, 0, stream>>>(Wih2, Whh2, bih2, bhh2, v, h1n, h2, c2, h2n, out_h2, out_c2);
  k_out<<<8000, 256, 0, stream>>>(linw, linb, h2n, out_o);
}